// Round 5
// baseline (946.075 us; speedup 1.0000x reference)
//
#include <hip/hip_runtime.h>
#include <hip/hip_bf16.h>
#include <math.h>

// Problem constants (B=4, T=1024, H=1024, V=32000)
constexpr int kH   = 1024;
constexpr int kV   = 32000;
constexpr int kTok = 4096;    // B*T
constexpr int BM   = 256;
constexpr int BN   = 256;
constexpr int BK   = 64;      // f16 elements per K-step
constexpr int NT   = kH / BK;    // 16 K-tiles
constexpr int NVT  = kV / BN;    // 125
constexpr int NMT  = kTok / BM;  // 16

typedef _Float16 f16x8  __attribute__((ext_vector_type(8)));
typedef float    f32x16 __attribute__((ext_vector_type(16)));

typedef __attribute__((address_space(1))) const void gvoid_t;
typedef __attribute__((address_space(3))) void lvoid_t;

// fp32 -> f16 with XOR-swizzled 16B blocks (X operand): within each 64-elem
// K-chunk, logical block c of row r lands at physical block c ^ (r & 7).
// GEMM staging stays linear (global_load_lds requirement) while ds_read_b128
// fragment reads spread across bank groups.
__global__ __launch_bounds__(256) void convert_x_kernel(
    const float* __restrict__ src, _Float16* __restrict__ dst)
{
  int idx = blockIdx.x * 256 + threadIdx.x;   // one 8-elem block per thread
  int row = idx >> 7;                          // kH/8 = 128 blocks per row
  int blk = idx & 127;
  int chunk = blk >> 3;                        // 64-elem chunk (16 per row)
  int c = blk & 7;
  int p = c ^ (row & 7);
  const float* s = src + ((size_t)row << 10) + (blk << 3);
  float4 v0 = *(const float4*)s;
  float4 v1 = *(const float4*)(s + 4);
  f16x8 o = { (_Float16)v0.x, (_Float16)v0.y, (_Float16)v0.z, (_Float16)v0.w,
              (_Float16)v1.x, (_Float16)v1.y, (_Float16)v1.z, (_Float16)v1.w };
  *(f16x8*)&dst[((size_t)row << 10) + (chunk << 6) + (p << 3)] = o;
}

// fp32 -> f16 in MFMA A-operand FRAGMENT order (W operand). Fragment (vg, s)
// is a 1KB block: lane l holds W[vg*32 + (l&31)][s*16 + (l>>5)*8 .. +8).
// The GEMM loads these with fully-coalesced global_load_dwordx4 -> VGPRs,
// so W never touches LDS.
__global__ __launch_bounds__(256) void convert_w_kernel(
    const float* __restrict__ src, _Float16* __restrict__ dst)
{
  int t    = blockIdx.x * 256 + threadIdx.x;   // one 16B fragment slot
  int lane = t & 63;
  int s    = (t >> 6) & 63;
  int vg   = t >> 12;                           // 0..999
  int row  = vg * 32 + (lane & 31);
  int k0   = s * 16 + (lane >> 5) * 8;
  const float* p = src + (size_t)row * kH + k0;
  float4 v0 = *(const float4*)p;
  float4 v1 = *(const float4*)(p + 4);
  f16x8 o = { (_Float16)v0.x, (_Float16)v0.y, (_Float16)v0.z, (_Float16)v0.w,
              (_Float16)v1.x, (_Float16)v1.y, (_Float16)v1.z, (_Float16)v1.w };
  *(f16x8*)&dst[(size_t)t * 8] = o;
}

// ---------------------------------------------------------------------------
// Fused GEMM + per-row (max, sum-exp) partials over each 256-col vocab tile.
// 256x256 tile, BK=64, 8 waves (2 tok-halves x 4 voc-quarters), per-wave
// output 64 voc x 128 tok via mfma_f32_32x32x16_f16 (A = vocab fragments
// from REGISTERS, B = token fragments from LDS). W fragments are loaded
// directly from fragment-ordered global memory (L2/L3-resident, coalesced
// 1KB per instruction) -> LDS holds only X (2 x 32KB double-buffer), cutting
// LDS traffic 3x vs both-operand staging. All pipelining is intra-tile
// (issue next tile's loads, compute, drain), so plain __syncthreads()
// (vmcnt(0)+lgkmcnt(0)+s_barrier) is exactly the required sync -- no inline
// asm anywhere.
// ---------------------------------------------------------------------------
__global__ __launch_bounds__(512, 2) void lse_gemm_kernel(
    const _Float16* __restrict__ X0, const _Float16* __restrict__ W0,
    const _Float16* __restrict__ X1, const _Float16* __restrict__ W1,
    float2* __restrict__ P0, float2* __restrict__ P1)
{
  __shared__ _Float16 Xs[2][BM * BK];   // 2 x 32 KB

  const _Float16* Xp = blockIdx.z ? X1 : X0;
  const _Float16* Wp = blockIdx.z ? W1 : W0;   // fragment-ordered
  float2* Pp = blockIdx.z ? P1 : P0;

  const int tid  = threadIdx.x;
  const int wave = tid >> 6;
  const int lane = tid & 63;
  const int l31  = lane & 31;
  const int h    = lane >> 5;        // k-half within K=16 step
  const int ll7  = lane & 7;         // == (row & 7) for all fragment rows
  const int wr   = wave >> 2;        // 0..1 : token half (128 tokens)
  const int wc   = wave & 3;         // 0..3 : vocab quarter (64 rows)
  const int srow = lane >> 3;        // staging row within 8-row group
  const int sblk = lane & 7;         // staging 16B block within row chunk

  const int m_base = blockIdx.x * BM;

  // X staging base: each global_load_lds covers 8 rows x 128B (1KB/wave).
  const _Float16* gX = Xp + (size_t)(m_base + wave * 8 + srow) * kH + sblk * 8;
  // W fragment base for this wave: vg0 = blockIdx.y*8 + wc*2; fragment (j,s)
  // at gW + (j*64 + s)*512 f16 (1KB blocks, lane-contiguous).
  const _Float16* gW = Wp + (size_t)(blockIdx.y * 8 + wc * 2) * 32768
                          + (size_t)lane * 8;

  // Token-fragment LDS addressing (f16 units); row stride 64 f16 = 128B.
  // K-step s, k-half h: logical 16B block = s*2+h, physical = (s*2+h)^(row&7),
  // and row&7 == ll7 for every fragment row.
  const int baseT = (wr * 128 + l31) * BK;   // + f*32*BK + offK[s]
  int offK[4];
#pragma unroll
  for (int s = 0; s < 4; ++s) offK[s] = (((s * 2 + h) ^ ll7) << 3);

  f32x16 acc[2][4];
#pragma unroll
  for (int j = 0; j < 2; ++j)
#pragma unroll
    for (int i = 0; i < 4; ++i)
#pragma unroll
      for (int r = 0; r < 16; ++r) acc[j][i][r] = 0.f;

  f16x8 vfA[2][4], vfB[2][4];   // W fragments, double-buffered in registers
  f16x8 tfa[4], tfb[4];         // token fragments (transient)

#define STG(c, kt) do {                                                             \
    _Pragma("unroll")                                                               \
    for (int i = 0; i < 4; ++i)                                                     \
      __builtin_amdgcn_global_load_lds(                                             \
          (gvoid_t*)(gX + (size_t)(i * 64) * kH + (kt) * 64),                       \
          (lvoid_t*)&Xs[c][(i * 64 + wave * 8) * 64], 16, 0, 0);                    \
  } while (0)

#define RDW(vf, kt) do {                                                            \
    _Pragma("unroll")                                                               \
    for (int j = 0; j < 2; ++j)                                                     \
      _Pragma("unroll")                                                             \
      for (int ss = 0; ss < 4; ++ss)                                                \
        vf[j][ss] = *(const f16x8*)(gW + (size_t)(j * 64 + (kt) * 4 + ss) * 512);   \
  } while (0)

#define RDTF(tf, c, f) do {                                                         \
    _Pragma("unroll")                                                               \
    for (int ss = 0; ss < 4; ++ss)                                                  \
      tf[ss] = *(const f16x8*)&Xs[c][baseT + (f) * 32 * BK + offK[ss]];             \
  } while (0)

#define MM(g, TF, VF) do {                                                          \
    __builtin_amdgcn_s_setprio(1);                                                  \
    _Pragma("unroll")                                                               \
    for (int ss = 0; ss < 4; ++ss) {                                                \
      acc[0][g] = __builtin_amdgcn_mfma_f32_32x32x16_f16(VF[0][ss], TF[ss], acc[0][g], 0, 0, 0); \
      acc[1][g] = __builtin_amdgcn_mfma_f32_32x32x16_f16(VF[1][ss], TF[ss], acc[1][g], 0, 0, 0); \
    }                                                                               \
    __builtin_amdgcn_s_setprio(0);                                                  \
  } while (0)

// Tile body: 16 ds_read_b128 + 32 MFMA, no internal barriers -> compiler
// software-pipelines reads of frag f+1 under MFMA of frag f (lgkmcnt-counted).
#define COMPUTE(c, VF) do {                                                         \
    RDTF(tfa, c, 0); RDTF(tfb, c, 1);                                               \
    MM(0, tfa, VF);  RDTF(tfa, c, 2);                                               \
    MM(1, tfb, VF);  RDTF(tfb, c, 3);                                               \
    MM(2, tfa, VF);  MM(3, tfb, VF);                                                \
  } while (0)

  // Prologue: tile 0's X (4 lds-loads) + W (8 reg-loads) in flight.
  STG(0, 0); RDW(vfA, 0);
  __syncthreads();                  // drains vmcnt -> tile 0 resident

  for (int kt = 0; kt < NT; kt += 2) {
    // ---- tile kt (buf0, vfA); prefetch kt+1 under compute ----
    STG(1, kt + 1); RDW(vfB, kt + 1);
    COMPUTE(0, vfA);
    __syncthreads();                // kt+1 landed; all waves done with buf0
    // ---- tile kt+1 (buf1, vfB); prefetch kt+2 under compute ----
    if (kt < NT - 2) { STG(0, kt + 2); RDW(vfA, kt + 2); }
    COMPUTE(1, vfB);
    __syncthreads();                // kt+2 landed; all waves done with buf1
  }

#undef STG
#undef RDW
#undef RDTF
#undef MM
#undef COMPUTE

  // Epilogue. acc[j][i][reg] = logits[vocab = v_base + wc*64 + j*32 + rr]
  //                                  [token = m_base + wr*128 + i*32 + l31]
  // with rr = (reg&3) + 8*(reg>>2) + 4*h. Lane l and l^32 share the token and
  // cover complementary vocab rows -> 32 local values + one xor-32 combine.
  float* redm = (float*)&Xs[0][0];   // [4 wc][256 tok]
  float* reds = redm + 4 * 256;

#pragma unroll
  for (int i = 0; i < 4; ++i) {
    float m = acc[0][i][0];
#pragma unroll
    for (int r = 1; r < 16; ++r) m = fmaxf(m, acc[0][i][r]);
#pragma unroll
    for (int r = 0; r < 16; ++r) m = fmaxf(m, acc[1][i][r]);
    float s = 0.f;
#pragma unroll
    for (int r = 0; r < 16; ++r) s += __expf(acc[0][i][r] - m);
#pragma unroll
    for (int r = 0; r < 16; ++r) s += __expf(acc[1][i][r] - m);
    float om = __shfl_xor(m, 32, 64);
    float os = __shfl_xor(s, 32, 64);
    float nm = fmaxf(m, om);
    s = s * __expf(m - nm) + os * __expf(om - nm);
    m = nm;
    if (lane < 32) {
      redm[wc * 256 + wr * 128 + i * 32 + lane] = m;
      reds[wc * 256 + wr * 128 + i * 32 + lane] = s;
    }
  }
  __syncthreads();
  if (tid < 256) {
    float M = redm[tid], S = reds[tid];
#pragma unroll
    for (int w = 1; w < 4; ++w) {
      float m2 = redm[w * 256 + tid], s2 = reds[w * 256 + tid];
      float nm = fmaxf(M, m2);
      S = S * __expf(M - nm) + s2 * __expf(m2 - nm);
      M = nm;
    }
    Pp[(size_t)blockIdx.y * kTok + m_base + tid] = make_float2(M, S);
  }
}

// Exact fp32 selected-logit from the ORIGINAL fp32 inputs.
__global__ __launch_bounds__(256) void sel_kernel(
    const float* __restrict__ X0, const float* __restrict__ W0,
    const float* __restrict__ X1, const float* __restrict__ W1,
    const int* __restrict__ ids, float* __restrict__ sel0, float* __restrict__ sel1)
{
  const int model = blockIdx.y;
  const float* X = model ? X1 : X0;
  const float* W = model ? W1 : W0;
  float* out = model ? sel1 : sel0;
  const int wave = threadIdx.x >> 6, lane = threadIdx.x & 63;
  const int t  = blockIdx.x * 4 + wave;
  const int id = ids[t];
  const float* xr = X + (size_t)t * kH;
  const float* wr = W + (size_t)id * kH;
  float s = 0.f;
#pragma unroll
  for (int r = 0; r < 4; ++r) {
    int idx = r * 256 + lane * 4;
    float4 a = *(const float4*)&xr[idx];
    float4 b = *(const float4*)&wr[idx];
    s += a.x * b.x + a.y * b.y + a.z * b.z + a.w * b.w;
  }
#pragma unroll
  for (int st = 32; st; st >>= 1) s += __shfl_xor(s, st, 64);
  if (lane == 0) out[t] = s;
}

// Combine 125 partials/model -> lse; GRPO loss; reduce.
__global__ __launch_bounds__(256) void finalize_kernel(
    const float2* __restrict__ P0, const float2* __restrict__ P1,
    const float* __restrict__ sel0, const float* __restrict__ sel1,
    const float* __restrict__ adv, const int* __restrict__ mask,
    float* __restrict__ accum)
{
  const int t = blockIdx.x * 256 + threadIdx.x;
  float M0 = -INFINITY, S0 = 0.f, M1 = -INFINITY, S1 = 0.f;
  for (int i = 0; i < NVT; ++i) {
    float2 p = P0[(size_t)i * kTok + t];
    if (p.x > M0) { S0 = S0 * __expf(M0 - p.x) + p.y; M0 = p.x; }
    else          { S0 += p.y * __expf(p.x - M0); }
  }
  for (int i = 0; i < NVT; ++i) {
    float2 p = P1[(size_t)i * kTok + t];
    if (p.x > M1) { S1 = S1 * __expf(M1 - p.x) + p.y; M1 = p.x; }
    else          { S1 += p.y * __expf(p.x - M1); }
  }
  float lse0  = M0 + logf(S0);
  float lse1  = M1 + logf(S1);
  float logp  = sel0[t] - lse0;
  float rlogp = sel1[t] - lse1;
  float d  = rlogp - logp;
  float kl = __expf(d) - d - 1.f;
  // coef_1 = exp(logp - stopgrad(logp)) == 1, clip == 1 -> loss = -adv + beta*kl
  float a  = adv[t >> 10];
  float mv = (float)mask[t];
  float loss = (-a + 0.1f * kl) * mv;

#pragma unroll
  for (int st = 32; st; st >>= 1) {
    loss += __shfl_xor(loss, st, 64);
    mv   += __shfl_xor(mv, st, 64);
  }
  __shared__ float lsum[4], msum[4];
  const int wave = threadIdx.x >> 6, lane = threadIdx.x & 63;
  if (lane == 0) { lsum[wave] = loss; msum[wave] = mv; }
  __syncthreads();
  if (threadIdx.x == 0) {
    atomicAdd(&accum[0], lsum[0] + lsum[1] + lsum[2] + lsum[3]);
    atomicAdd(&accum[1], msum[0] + msum[1] + msum[2] + msum[3]);
  }
}

__global__ void scalar_kernel(const float* __restrict__ accum, float* __restrict__ out)
{
  out[0] = accum[0] / fmaxf(accum[1], 1.f);
}

extern "C" void kernel_launch(void* const* d_in, const int* in_sizes, int n_in,
                              void* d_out, int out_size, void* d_ws, size_t ws_size,
                              hipStream_t stream)
{
  const float* x    = (const float*)d_in[0];
  const float* w    = (const float*)d_in[1];
  const float* rx   = (const float*)d_in[2];
  const float* rw   = (const float*)d_in[3];
  const float* adv  = (const float*)d_in[4];
  const int*   ids  = (const int*)d_in[5];
  const int*   mask = (const int*)d_in[6];
  float* out = (float*)d_out;

  // Workspace layout (~152 MB): f16 copies + partials + sel + accum.
  char* ws = (char*)d_ws;
  _Float16* Xh  = (_Float16*)ws;                         // 8 MB (swizzled rows)
  _Float16* Wf  = Xh + (size_t)kTok * kH;                // 64 MB (fragment order)
  _Float16* RXh = Wf + (size_t)kV * kH;                  // 8 MB
  _Float16* RWf = RXh + (size_t)kTok * kH;               // 64 MB
  float2*   P0  = (float2*)(RWf + (size_t)kV * kH);      // 4 MB
  float2*   P1  = P0 + (size_t)NVT * kTok;               // 4 MB
  float*    sel0 = (float*)(P1 + (size_t)NVT * kTok);
  float*    sel1 = sel0 + kTok;
  float*    accum = sel1 + kTok;

  hipMemsetAsync(accum, 0, 2 * sizeof(float), stream);

  convert_x_kernel<<<kTok * 128 / 256, 256, 0, stream>>>(x,  Xh);
  convert_x_kernel<<<kTok * 128 / 256, 256, 0, stream>>>(rx, RXh);
  convert_w_kernel<<<kV / 32 * 64 * 64 / 256, 256, 0, stream>>>(w,  Wf);
  convert_w_kernel<<<kV / 32 * 64 * 64 / 256, 256, 0, stream>>>(rw, RWf);

  sel_kernel<<<dim3(kTok / 4, 2), 256, 0, stream>>>(x, w, rx, rw, ids, sel0, sel1);

  lse_gemm_kernel<<<dim3(NMT, NVT, 2), 512, 0, stream>>>(Xh, Wf, RXh, RWf, P0, P1);

  finalize_kernel<<<kTok / 256, 256, 0, stream>>>(P0, P1, sel0, sel1, adv, mask, accum);
  scalar_kernel<<<1, 1, 0, stream>>>(accum, out);
}